// Round 11
// baseline (218.462 us; speedup 1.0000x reference)
//
#include <hip/hip_runtime.h>
#include <stdint.h>

#define ROWS   4096
#define NCOL   8192
#define TARGET 7680
#define NW     (NCOL - TARGET + 1)   // 513 windows
#define NT     512                   // threads per block (8 waves)
#define VPT    (NCOL / NT)           // 16 values per thread (in VGPRs)
#define NB     2048                  // histogram bins
#define BPT    (NB / NT)             // 4 bins per thread in scan
#define NWAVE  (NT / 64)             // 8 waves
#define SCAP   2048                  // sorted-buffer capacity
#define MAXS   (SCAP / NT)           // max slots per thread in fixup (4)

// Fast path: threshold pre-filter. Only tail values (rank<513 from either end)
// are ever needed. For N(0,1)-like rows, P(|v|>1.38)=8.38%/side: E[cnt]=686,
// sigma=25 -> cnt>=513 at 6.9 sigma, tot<=2048 at >9 sigma. Guard checks both;
// any other distribution takes the exact round-6 fallback (block-uniform).
#define T_LO   (-1.38f)
#define T_HI   (1.38f)
#define NBS    1024                  // fast-path bins per side
#define BMIN   (-4.0f)               // bottom map [BMIN,T_LO); clamp outside
#define BSC    ((float)NBS / (T_LO - BMIN))   // ~391 bins/unit -> ~0.7 elem/bin

struct Smem {
    uint32_t hist[NB];       // transposed: logical bin b at ((b&3)<<9)|(b>>2)
    float    sorted[SCAP];   // scattered candidates (unordered within bin)
    float    sorted2[SCAP];  // fixup output: exact sorted tails
    uint32_t wsum[NWAVE];
    uint32_t cntlo[NWAVE], cnthi[NWAVE];   // per-wave threshold counts
    uint32_t res[4];         // fallback: [0]=B_lo [1]=cntB [2]=B_hi [3]=topBase
    float    fmin[NWAVE], fmax[NWAVE];     // fallback only
};

// transposed physical index: scan reads hist[(j<<9)|tid] lane-consecutively
// (conflict-free); atomics hash on bin bits 2..6. (round-7: identity layout
// 2.4x'd bank conflicts -> keep transposed)
__device__ __forceinline__ int HIX(int b) { return ((b & 3) << 9) | (b >> 2); }

// fast-path monotone tail maps (clamped; exactness restored by in-bin sort)
__device__ __forceinline__ int bin_bot(float v) {
    int b = (int)((v - BMIN) * BSC);
    b = b < 0 ? 0 : b;
    return b > NBS - 1 ? NBS - 1 : b;
}
__device__ __forceinline__ int bin_top(float v) {
    int b = (int)((v - T_HI) * BSC);
    b = b < 0 ? 0 : b;
    b = b > NBS - 1 ? NBS - 1 : b;
    return NBS + b;
}
// fallback dynamic map
__device__ __forceinline__ int binf(float v, float mn, float s) {
    int b = (int)((v - mn) * s);
    b = b < 0 ? 0 : b;
    return b > NB - 1 ? NB - 1 : b;
}

// NT=512 confirmed (round-8: NT=256's 48-word state thrashes the allocator).
// launch_bounds(512,4): 128-VGPR budget, no forced ceiling (round-3: forced 64
// spilled). Grid 4096, one row/block (round-5: small-grid convoys lockstep).
__global__ __launch_bounds__(NT, 4)
void recall_window_kernel(const float* __restrict__ x, float* __restrict__ out) {
    __shared__ Smem sm;
    const int tid = threadIdx.x;
    const int row = blockIdx.x;
    const int lane = tid & 63, wid = tid >> 6;

    // ---- Load row (coalesced 16B) + threshold counts (registers only) ----
    float v[VPT];
    uint32_t clo = 0, chi = 0;
    const float4* xv = (const float4*)(x + (size_t)row * NCOL);
    #pragma unroll
    for (int j = 0; j < VPT / 4; j++) {
        float4 t = xv[tid + j * NT];
        v[4 * j + 0] = t.x; v[4 * j + 1] = t.y;
        v[4 * j + 2] = t.z; v[4 * j + 3] = t.w;
        clo += (t.x < T_LO) + (t.y < T_LO) + (t.z < T_LO) + (t.w < T_LO);
        chi += (t.x > T_HI) + (t.y > T_HI) + (t.z > T_HI) + (t.w > T_HI);
    }
    #pragma unroll
    for (int off = 32; off > 0; off >>= 1) {
        clo += __shfl_down(clo, off, 64);
        chi += __shfl_down(chi, off, 64);
    }
    if (lane == 0) { sm.cntlo[wid] = clo; sm.cnthi[wid] = chi; }
    {   // zero hist: one b128 store per thread
        uint4 z; z.x = 0; z.y = 0; z.z = 0; z.w = 0;
        *(uint4*)&sm.hist[tid * 4] = z;
    }
    __syncthreads();                                             // S1
    uint32_t cnt_lo = 0, cnt_hi = 0;
    #pragma unroll
    for (int w = 0; w < NWAVE; w++) { cnt_lo += sm.cntlo[w]; cnt_hi += sm.cnthi[w]; }
    const uint32_t totF = cnt_lo + cnt_hi;
    const bool fast = (cnt_lo >= NW) && (cnt_hi >= NW) && (totF <= SCAP);

    if (fast) {   // block-uniform
        // ---- hist: candidates only (~1370 atomics vs 8192) ----
        #pragma unroll
        for (int j = 0; j < VPT; j++) {
            float val = v[j];
            bool bot = val < T_LO, top = val > T_HI;
            if (bot | top) {
                int b = bot ? bin_bot(val) : bin_top(val);
                atomicAdd(&sm.hist[HIX(b)], 1u);
            }
        }
        __syncthreads();                                         // S2

        // ---- scan: prefix only -- NO rank-locate needed (cnt_lo = split) ----
        uint32_t h[BPT], s0 = 0;
        #pragma unroll
        for (int j = 0; j < BPT; j++) { h[j] = sm.hist[(j << 9) | tid]; s0 += h[j]; }
        uint32_t sc = s0;
        #pragma unroll
        for (int off = 1; off < 64; off <<= 1) {
            uint32_t n = __shfl_up(sc, off, 64);
            if (lane >= off) sc += n;
        }
        if (lane == 63) sm.wsum[wid] = sc;
        __syncthreads();                                         // S3
        uint32_t woff = 0;
        #pragma unroll
        for (int w = 0; w < NWAVE; w++) if (w < wid) woff += sm.wsum[w];
        uint32_t run = sc + woff - s0;       // exclusive prefix
        #pragma unroll
        for (int j = 0; j < BPT; j++) { sm.hist[(j << 9) | tid] = run; run += h[j]; }
        __syncthreads();                                         // S4

        // ---- scatter: bottom bins 0..1023 -> slots [0,cnt_lo) ascending;
        //      top bins 1024..2047 -> slots [cnt_lo,tot) ascending ----
        #pragma unroll
        for (int j = 0; j < VPT; j++) {
            float val = v[j];
            bool bot = val < T_LO, top = val > T_HI;
            if (bot | top) {
                int b = bot ? bin_bot(val) : bin_top(val);
                uint32_t pos = atomicAdd(&sm.hist[HIX(b)], 1u);
                if (pos < SCAP) sm.sorted[pos] = val;
            }
        }
        __syncthreads();                                         // S5
        // hist[b] now = inclusive end of bin b (continuous prefix both sides)

        // ---- fixup: ~0.7 elem/bin -> in-bin scans mostly length-1 ----
        #pragma unroll
        for (int it = 0; it < MAXS; it++) {
            int s = tid + it * NT;
            if (s < (int)totF) {
                float vv = sm.sorted[s];
                int b = (s < (int)cnt_lo) ? bin_bot(vv) : bin_top(vv);
                uint32_t en = sm.hist[HIX(b)];
                uint32_t st = (b == 0) ? 0u : sm.hist[HIX(b - 1)];
                uint32_t r = 0;
                if (en - st > 1) {
                    for (uint32_t q = st; q < en; q++) {
                        float u = sm.sorted[q];
                        r += (u < vv) || (u == vv && (int)q < s);
                    }
                }
                sm.sorted2[st + r] = vv;
            }
        }
        __syncthreads();                                         // S6

        // sorted2[0..cnt_lo) = ranks 0..cnt_lo-1; sorted2[cnt_lo..tot) =
        // ranks 8192-cnt_hi..8191. window i: left=sorted2[i],
        // right = rank 7679+i -> slot tot-513+i = topstart+i.
        if (wid == 0) {
            const int topstart = (int)totF - NW;
            float lbest = __int_as_float(0x7F800000);
            int   lidx  = 0x7FFFFFFF;
            for (int i = lane; i < NW; i += 64) {
                float len = sm.sorted2[topstart + i] - sm.sorted2[i];
                if (len < lbest) { lbest = len; lidx = i; }
            }
            #pragma unroll
            for (int off = 32; off > 0; off >>= 1) {
                float v2 = __shfl_down(lbest, off, 64);
                int   i2 = __shfl_down(lidx,  off, 64);
                if (v2 < lbest || (v2 == lbest && i2 < lidx)) { lbest = v2; lidx = i2; }
            }
            if (lane == 0) {
                out[row]        = sm.sorted2[lidx];
                out[ROWS + row] = sm.sorted2[topstart + lidx];
            }
        }
        return;
    }

    // ======== FALLBACK: exact round-6 path (any distribution) ========
    float mn = v[0], mx = v[0];
    #pragma unroll
    for (int j = 1; j < VPT; j++) { mn = fminf(mn, v[j]); mx = fmaxf(mx, v[j]); }
    #pragma unroll
    for (int off = 32; off > 0; off >>= 1) {
        mn = fminf(mn, __shfl_down(mn, off, 64));
        mx = fmaxf(mx, __shfl_down(mx, off, 64));
    }
    if (lane == 0) { sm.fmin[wid] = mn; sm.fmax[wid] = mx; }
    {   // re-zero hist
        uint4 z; z.x = 0; z.y = 0; z.z = 0; z.w = 0;
        *(uint4*)&sm.hist[tid * 4] = z;
    }
    __syncthreads();
    #pragma unroll
    for (int w = 0; w < NWAVE; w++) {
        mn = fminf(mn, sm.fmin[w]);
        mx = fmaxf(mx, sm.fmax[w]);
    }
    if (!(mx > mn)) {   // all values equal (uniform early-out)
        if (tid == 0) { out[row] = mn; out[ROWS + row] = mn; }
        return;
    }
    const float amn = mn, asc = (float)NB / (mx - mn);

    #pragma unroll
    for (int j = 0; j < VPT; j++)
        atomicAdd(&sm.hist[HIX(binf(v[j], amn, asc))], 1u);
    __syncthreads();

    uint32_t h[BPT], s0 = 0;
    #pragma unroll
    for (int j = 0; j < BPT; j++) { h[j] = sm.hist[(j << 9) | tid]; s0 += h[j]; }
    uint32_t sc = s0;
    #pragma unroll
    for (int off = 1; off < 64; off <<= 1) {
        uint32_t n = __shfl_up(sc, off, 64);
        if (lane >= off) sc += n;
    }
    if (lane == 63) sm.wsum[wid] = sc;
    __syncthreads();
    uint32_t woff = 0;
    #pragma unroll
    for (int w = 0; w < NWAVE; w++) if (w < wid) woff += sm.wsum[w];
    const uint32_t incl = sc + woff, excl = incl - s0;
    const uint32_t ka = NW - 1, kb = TARGET - 1;
    if (ka >= excl && ka < incl) {
        uint32_t c = excl; bool done = false;
        #pragma unroll
        for (int j = 0; j < BPT; j++) {
            if (!done) {
                if (ka < c + h[j]) {
                    sm.res[0] = (uint32_t)(tid * BPT + j);
                    sm.res[1] = c + h[j];
                    done = true;
                } else c += h[j];
            }
        }
    }
    if (kb >= excl && kb < incl) {
        uint32_t c = excl; bool done = false;
        #pragma unroll
        for (int j = 0; j < BPT; j++) {
            if (!done) {
                if (kb < c + h[j]) {
                    sm.res[2] = (uint32_t)(tid * BPT + j);
                    sm.res[3] = c;
                    done = true;
                } else c += h[j];
            }
        }
    }
    {
        uint32_t run = excl;
        #pragma unroll
        for (int j = 0; j < BPT; j++) { sm.hist[(j << 9) | tid] = run; run += h[j]; }
    }
    __syncthreads();
    const int      B_lo    = (int)sm.res[0];
    const uint32_t cntB    = sm.res[1];
    const int      B_hi    = (int)sm.res[2];
    const uint32_t topBase = sm.res[3];
    const uint32_t shiftT  = cntB - topBase;
    uint32_t tot = cntB + (uint32_t)NCOL - topBase;
    if (tot > SCAP) tot = SCAP;

    #pragma unroll
    for (int j = 0; j < VPT; j++) {
        float val = v[j];
        int b = binf(val, amn, asc);
        if (b <= B_lo || b >= B_hi) {
            uint32_t pos = atomicAdd(&sm.hist[HIX(b)], 1u);
            if (b >= B_hi) pos += shiftT;
            if (pos < SCAP) sm.sorted[pos] = val;
        }
    }
    __syncthreads();

    #pragma unroll
    for (int it = 0; it < MAXS; it++) {
        int s = tid + it * NT;
        if (s < (int)tot) {
            float vv = sm.sorted[s];
            int b = binf(vv, amn, asc);
            uint32_t en = sm.hist[HIX(b)];
            uint32_t st;
            if (s < (int)cntB) {
                st = (b == 0) ? 0u : sm.hist[HIX(b - 1)];
            } else {
                st = (b == B_hi) ? topBase : sm.hist[HIX(b - 1)];
                st += shiftT; en += shiftT;
            }
            if (en > tot) en = tot;
            uint32_t r = 0;
            if (en - st > 1) {
                for (uint32_t q = st; q < en; q++) {
                    float u = sm.sorted[q];
                    r += (u < vv) || (u == vv && (int)q < s);
                }
            }
            uint32_t d = st + r;
            if (d < SCAP) sm.sorted2[d] = vv;
        }
    }
    __syncthreads();

    if (wid == 0) {
        const int topstart = (int)tot - NW;
        float lbest = __int_as_float(0x7F800000);
        int   lidx  = 0x7FFFFFFF;
        for (int i = lane; i < NW; i += 64) {
            float len = sm.sorted2[topstart + i] - sm.sorted2[i];
            if (len < lbest) { lbest = len; lidx = i; }
        }
        #pragma unroll
        for (int off = 32; off > 0; off >>= 1) {
            float v2 = __shfl_down(lbest, off, 64);
            int   i2 = __shfl_down(lidx,  off, 64);
            if (v2 < lbest || (v2 == lbest && i2 < lidx)) { lbest = v2; lidx = i2; }
        }
        if (lane == 0) {
            out[row]        = sm.sorted2[lidx];
            out[ROWS + row] = sm.sorted2[topstart + lidx];
        }
    }
}

extern "C" void kernel_launch(void* const* d_in, const int* in_sizes, int n_in,
                              void* d_out, int out_size, void* d_ws, size_t ws_size,
                              hipStream_t stream) {
    const float* x = (const float*)d_in[0];
    float* out = (float*)d_out;
    recall_window_kernel<<<ROWS, NT, 0, stream>>>(x, out);
}

// Round 12
// 217.676 us; speedup vs baseline: 1.0036x; 1.0036x over previous
//
#include <hip/hip_runtime.h>
#include <stdint.h>

#define ROWS   4096
#define NCOL   8192
#define TARGET 7680
#define NW     (NCOL - TARGET + 1)   // 513 windows
#define NT     256                   // threads per block (4 waves)
#define VPT    (NCOL / NT)           // 32 values per thread (STREAMED, not stored)
#define NB     2048                  // histogram bins
#define BPT    (NB / NT)             // 8 bins per thread in scan
#define NWAVE  (NT / 64)             // 4 waves
#define SCAP   2048                  // sorted-buffer capacity (== NB, aliases)
#define MAXS   (SCAP / NT)           // 8 fixup slots per thread
// Fixed bin map [-4,4): 256 bins/unit (round-10 validated: same tail-bin
// density as dynamic). Outliers clamp (map stays monotone, ranks exact);
// rows where candidate bins overflow SCAP take the exact dynamic fallback.
#define FMN    (-4.0f)
#define FSC    ((float)NB / 8.0f)

struct Smem {
    union {                  // fixup OUTPUT aliases hist: after the bases are
        uint32_t hist[NB];   // consumed, sortedF[d] receives the sorted tails
        float    sortedF[NB];
    };
    float    sorted[SCAP];   // scattered candidates (unordered within bin)
    uint32_t wsum[NWAVE];
    uint32_t res[4];         // [0]=B_lo [1]=cntB(incl) [2]=B_hi [3]=topBase(excl)
    float    fmin[NWAVE], fmax[NWAVE];   // fallback only
};
// total LDS = 8K + 8K + ~0.1K = 16.5 KB -> 9 blocks LDS-wise; wave-cap 8/CU.

// Monotone clamped binning: exact rank-partition for ANY (mn, s).
__device__ __forceinline__ int binf(float v, float mn, float s) {
    int b = (int)((v - mn) * s);
    b = b < 0 ? 0 : b;
    return b > NB - 1 ? NB - 1 : b;
}
// transposed physical index (BPT=8 form): scan reads hist[(j<<8)|tid]
// lane-consecutively (conflict-free); atomics hash on bin bits 3..7.
// (round-7: identity layout 2.4x'd bank conflicts -> keep transposed)
__device__ __forceinline__ int HIX(int b) { return ((b & 7) << 8) | (b >> 3); }

// Full pipeline for one bin-map. Assumes hist is zeroed + barrier'd.
// allow_fail: return false (uniformly, after S4) if tot > SCAP.
__device__ __forceinline__ bool do_row(Smem& sm, const float4* __restrict__ xv,
                                       float amn, float asc, bool allow_fail,
                                       float* __restrict__ out, int row,
                                       int tid, int lane, int wid) {
    // ---- Pass A: STREAMING hist (no value caching -> ~50 VGPR total) ----
    #pragma unroll
    for (int q = 0; q < VPT / 4; q++) {
        float4 t = xv[tid + q * NT];
        atomicAdd(&sm.hist[HIX(binf(t.x, amn, asc))], 1u);
        atomicAdd(&sm.hist[HIX(binf(t.y, amn, asc))], 1u);
        atomicAdd(&sm.hist[HIX(binf(t.z, amn, asc))], 1u);
        atomicAdd(&sm.hist[HIX(binf(t.w, amn, asc))], 1u);
    }
    __syncthreads();                                             // S2

    // ---- scan + locate rank bins + write scatter bases ----
    uint32_t h[BPT], s0 = 0;
    #pragma unroll
    for (int j = 0; j < BPT; j++) { h[j] = sm.hist[(j << 8) | tid]; s0 += h[j]; }
    uint32_t sc = s0;
    #pragma unroll
    for (int off = 1; off < 64; off <<= 1) {
        uint32_t n = __shfl_up(sc, off, 64);
        if (lane >= off) sc += n;
    }
    if (lane == 63) sm.wsum[wid] = sc;
    __syncthreads();                                             // S3
    uint32_t woff = 0;
    #pragma unroll
    for (int w = 0; w < NWAVE; w++) if (w < wid) woff += sm.wsum[w];
    const uint32_t incl = sc + woff, excl = incl - s0;
    const uint32_t ka = NW - 1, kb = TARGET - 1;
    if (ka >= excl && ka < incl) {           // bin of rank 512 (bottom tail end)
        uint32_t c = excl; bool done = false;
        #pragma unroll
        for (int j = 0; j < BPT; j++) {
            if (!done) {
                if (ka < c + h[j]) {
                    sm.res[0] = (uint32_t)(tid * BPT + j);
                    sm.res[1] = c + h[j];    // cntB = inclusive prefix at B_lo
                    done = true;
                } else c += h[j];
            }
        }
    }
    if (kb >= excl && kb < incl) {           // bin of rank 7679 (top tail start)
        uint32_t c = excl; bool done = false;
        #pragma unroll
        for (int j = 0; j < BPT; j++) {
            if (!done) {
                if (kb < c + h[j]) {
                    sm.res[2] = (uint32_t)(tid * BPT + j);
                    sm.res[3] = c;           // topBase = exclusive prefix at B_hi
                    done = true;
                } else c += h[j];
            }
        }
    }
    {   // overwrite counts with exclusive-prefix bases (independent of res)
        uint32_t run = excl;
        #pragma unroll
        for (int j = 0; j < BPT; j++) { sm.hist[(j << 8) | tid] = run; run += h[j]; }
    }
    __syncthreads();                                             // S4
    const int      B_lo    = (int)sm.res[0];
    const uint32_t cntB    = sm.res[1];
    const int      B_hi    = (int)sm.res[2];
    const uint32_t topBase = sm.res[3];
    const uint32_t shiftT  = cntB - topBase;     // mod-2^32
    uint32_t tot = cntB + (uint32_t)NCOL - topBase;   // uniform (from res)
    if (allow_fail && tot > SCAP) return false;       // uniform exit
    if (tot > SCAP) tot = SCAP;   // dup-heavy worst case (parity w/ prior)

    // ---- Pass B: RELOAD row (L3-resident: 134MB < 256MB) + scatter ----
    #pragma unroll
    for (int q = 0; q < VPT / 4; q++) {
        float4 t = xv[tid + q * NT];
        #pragma unroll
        for (int c4 = 0; c4 < 4; c4++) {
            float val = c4 == 0 ? t.x : (c4 == 1 ? t.y : (c4 == 2 ? t.z : t.w));
            int b = binf(val, amn, asc);
            if (b <= B_lo || b >= B_hi) {
                uint32_t pos = atomicAdd(&sm.hist[HIX(b)], 1u);
                if (b >= B_hi) pos += shiftT;
                if (pos < SCAP) sm.sorted[pos] = val;
            }
        }
    }
    __syncthreads();                                             // S5
    // hist[b] now = inclusive end of bin b (unshifted for top side)

    // ---- Fix-up stage 1: full rank computation into registers ----
    float fvv[MAXS];
    int   tgt[MAXS];
    #pragma unroll
    for (int it = 0; it < MAXS; it++) {
        int s = tid + it * NT;
        tgt[it] = -1;
        if (s < (int)tot) {
            float vv = sm.sorted[s];
            int b = binf(vv, amn, asc);
            uint32_t en = sm.hist[HIX(b)];
            uint32_t st;
            if (s < (int)cntB) {
                st = (b == 0) ? 0u : sm.hist[HIX(b - 1)];
            } else {
                st = (b == B_hi) ? topBase : sm.hist[HIX(b - 1)];
                st += shiftT; en += shiftT;
            }
            if (en > tot) en = tot;
            uint32_t r = 0;
            if (en - st > 1) {
                for (uint32_t q = st; q < en; q++) {
                    float u = sm.sorted[q];
                    r += (u < vv) || (u == vv && (int)q < s);
                }
            }
            uint32_t d = st + r;
            if (d < SCAP) { tgt[it] = (int)d; fvv[it] = vv; }
        }
    }
    __syncthreads();                                             // S6
    // ---- stage 2: write sorted tails into the hist region (sortedF) ----
    #pragma unroll
    for (int it = 0; it < MAXS; it++)
        if (tgt[it] >= 0) sm.sortedF[tgt[it]] = fvv[it];
    __syncthreads();                                             // S7

    // sortedF[0..cntB) = ranks 0..cntB-1; sortedF[cntB..tot) = top tail.
    // window i: left = sortedF[i]; right = sortedF[tot - NW + i]
    if (wid == 0) {
        const int topstart = (int)tot - NW;      // >= 0 (cntB >= 513)
        float lbest = __int_as_float(0x7F800000);
        int   lidx  = 0x7FFFFFFF;
        for (int i = lane; i < NW; i += 64) {
            float len = sm.sortedF[topstart + i] - sm.sortedF[i];
            if (len < lbest) { lbest = len; lidx = i; }
        }
        #pragma unroll
        for (int off = 32; off > 0; off >>= 1) {
            float v2 = __shfl_down(lbest, off, 64);
            int   i2 = __shfl_down(lidx,  off, 64);
            if (v2 < lbest || (v2 == lbest && i2 < lidx)) { lbest = v2; lidx = i2; }
        }
        if (lane == 0) {
            out[row]        = sm.sortedF[lidx];
            out[ROWS + row] = sm.sortedF[topstart + lidx];
        }
    }
    return true;
}

// NT=256 + STREAMING: round-8's NT=256 failure was the 48-word register
// state (v[32]+binPk[16]) thrashing the allocator; streaming passes keep
// ~50 VGPR. LDS 16.5KB (sorted2 deleted via hist-union) -> wave-capped
// 8 blocks/CU = 32 waves if VGPR<=64. launch_bounds(256,4): 128 budget,
// no forced ceiling (round-3: forcing spilled). Grid 4096, one row/block
// (round-5: small-grid convoys lockstep).
__global__ __launch_bounds__(NT, 4)
void recall_window_kernel(const float* __restrict__ x, float* __restrict__ out) {
    __shared__ Smem sm;
    const int tid = threadIdx.x;
    const int row = blockIdx.x;
    const int lane = tid & 63, wid = tid >> 6;
    const float4* xv = (const float4*)(x + (size_t)row * NCOL);

    // ---- zero hist (two b128 stores), cheap barrier ----
    {
        uint4 z; z.x = 0; z.y = 0; z.z = 0; z.w = 0;
        *(uint4*)&sm.hist[tid * 4] = z;
        *(uint4*)&sm.hist[NB / 2 + tid * 4] = z;
    }
    __syncthreads();                                             // S1

    if (do_row(sm, xv, FMN, FSC, true, out, row, tid, lane, wid))
        return;

    // ---- FALLBACK: exact dynamic range (rare; streaming minmax) ----
    float mn = __int_as_float(0x7F800000), mx = -mn;
    #pragma unroll
    for (int q = 0; q < VPT / 4; q++) {
        float4 t = xv[tid + q * NT];
        mn = fminf(mn, fminf(fminf(t.x, t.y), fminf(t.z, t.w)));
        mx = fmaxf(mx, fmaxf(fmaxf(t.x, t.y), fmaxf(t.z, t.w)));
    }
    #pragma unroll
    for (int off = 32; off > 0; off >>= 1) {
        mn = fminf(mn, __shfl_down(mn, off, 64));
        mx = fmaxf(mx, __shfl_down(mx, off, 64));
    }
    if (lane == 0) { sm.fmin[wid] = mn; sm.fmax[wid] = mx; }
    {   // re-zero hist (all threads are past S4 reads of hist)
        uint4 z; z.x = 0; z.y = 0; z.z = 0; z.w = 0;
        *(uint4*)&sm.hist[tid * 4] = z;
        *(uint4*)&sm.hist[NB / 2 + tid * 4] = z;
    }
    __syncthreads();
    #pragma unroll
    for (int w = 0; w < NWAVE; w++) {
        mn = fminf(mn, sm.fmin[w]);
        mx = fmaxf(mx, sm.fmax[w]);
    }
    if (!(mx > mn)) {   // all values equal (uniform early-out)
        if (tid == 0) { out[row] = mn; out[ROWS + row] = mn; }
        return;
    }
    do_row(sm, xv, mn, (float)NB / (mx - mn), false, out, row, tid, lane, wid);
}

extern "C" void kernel_launch(void* const* d_in, const int* in_sizes, int n_in,
                              void* d_out, int out_size, void* d_ws, size_t ws_size,
                              hipStream_t stream) {
    const float* x = (const float*)d_in[0];
    float* out = (float*)d_out;
    recall_window_kernel<<<ROWS, NT, 0, stream>>>(x, out);
}